// Round 6
// baseline (4659.221 us; speedup 1.0000x reference)
//
#include <hip/hip_runtime.h>
#include <cstdint>
#include <math.h>

typedef float f32x4 __attribute__((ext_vector_type(4)));
typedef __bf16 bf16x8 __attribute__((ext_vector_type(8)));
typedef unsigned short u16x8 __attribute__((ext_vector_type(8)));
typedef unsigned short u16x4 __attribute__((ext_vector_type(4)));

typedef __attribute__((address_space(1))) const void* gas_cvptr;
typedef __attribute__((address_space(3))) void* las_vptr;

#define WAITV4 asm volatile("s_waitcnt vmcnt(4)" ::: "memory")
#define WAITV0 asm volatile("s_waitcnt vmcnt(0)" ::: "memory")
#define WAITL0 asm volatile("s_waitcnt lgkmcnt(0)" ::: "memory")
#define SB()   __builtin_amdgcn_sched_barrier(0)
#define BAR()  __builtin_amdgcn_s_barrier()

__device__ __forceinline__ unsigned short f32_to_bf16(float f) {
  uint32_t u = __builtin_bit_cast(uint32_t, f);
  u += 0x7FFFu + ((u >> 16) & 1u);   // round-to-nearest-even
  return (unsigned short)(u >> 16);
}

__device__ __forceinline__ bf16x8 ld_bf16x8(const unsigned short* p) {
  return __builtin_bit_cast(bf16x8, *(const u16x8*)p);
}

// ---------------- convert x: f32 -> bf16 ----------------
__global__ void cvt_x(const float* __restrict__ x, unsigned short* __restrict__ xb, int n4) {
  int stride = gridDim.x * blockDim.x;
  for (int i = blockIdx.x * blockDim.x + threadIdx.x; i < n4; i += stride) {
    float4 v = ((const float4*)x)[i];
    u16x4 o = { f32_to_bf16(v.x), f32_to_bf16(v.y), f32_to_bf16(v.z), f32_to_bf16(v.w) };
    ((u16x4*)xb)[i] = o;
  }
}

// ------------- transpose weights [K][N] f32 -> [N][K] bf16 -------------
__global__ void cvt_w(const float* __restrict__ wq, const float* __restrict__ wk,
                      const float* __restrict__ wv, const float* __restrict__ wo,
                      unsigned short* __restrict__ wqkvT, unsigned short* __restrict__ woT) {
  const int z = blockIdx.z;
  const float* __restrict__ w = (z == 0) ? wq : (z == 1) ? wk : (z == 2) ? wv : wo;
  unsigned short* __restrict__ out = (z < 3) ? (wqkvT + (size_t)z * 1024 * 1024) : woT;
  __shared__ float tile[64][65];
  const int r0 = blockIdx.y * 64;  // k dim
  const int c0 = blockIdx.x * 64;  // n dim
  const int t = threadIdx.x;
#pragma unroll
  for (int i = 0; i < 4; i++) {
    int row = (t >> 4) + i * 16;
    int col = (t & 15) * 4;
    float4 v = *(const float4*)&w[(size_t)(r0 + row) * 1024 + c0 + col];
    tile[row][col] = v.x; tile[row][col + 1] = v.y;
    tile[row][col + 2] = v.z; tile[row][col + 3] = v.w;
  }
  __syncthreads();
#pragma unroll
  for (int i = 0; i < 2; i++) {
    int nr = (t >> 3) + i * 32;
    int kc = (t & 7) * 8;
    u16x8 o;
#pragma unroll
    for (int j = 0; j < 8; j++) o[j] = f32_to_bf16(tile[kc + j][nr]);
    *(u16x8*)&out[(size_t)(c0 + nr) * 1024 + r0 + kc] = o;
  }
}

// per-tile fragment set: 12 x bf16x8 = 48 VGPR
struct Frags { bf16x8 afA[4], bfr[4], afB[4]; };

__device__ __forceinline__ void read_frags(Frags& f, const unsigned short* ab,
                                           const unsigned short* bb, int aRow0,
                                           int bRow0, int li, int koff) {
#pragma unroll
  for (int m = 0; m < 4; m++) f.afA[m] = ld_bf16x8(ab + (aRow0 + m * 16 + li) * 32 + koff);
#pragma unroll
  for (int n = 0; n < 4; n++) f.bfr[n] = ld_bf16x8(bb + (bRow0 + n * 16 + li) * 32 + koff);
#pragma unroll
  for (int m = 0; m < 4; m++)
    f.afB[m] = ld_bf16x8(ab + (aRow0 + 64 + m * 16 + li) * 32 + koff);
}

// ============ 256x256-tile GEMM, 2 blocks/CU: C = A[M][K] @ Bt[N][K]^T ============
// 512 threads = 8 waves (2 wm x 4 wn); wave tile 128x64; BK=32.
// 2 LDS buffers (64 KB total) -> 2 blocks/CU (16 waves), so a second independent
// barrier domain fills this block's barrier/waitcnt stalls (round-5 post-mortem:
// matrix pipe idle 60% at 1 block/CU).
// Per tile tt (one barrier): MFMA-B(tt-1) | lgkm0 | MFMA-A(tt) | vmcnt0 | BAR |
// STAGE(tt+2)->buf[tt&1] | ds_read frags(tt+1). WAR: buf[tt&1] readers did lgkm0
// before this BAR. RAW: each wave confirmed its own stage(tt+1) pre-BAR.
// LDS bank-conflict fix: physical 16B-chunk pc = lc ^ ((row>>1)&3), pre-swizzled
// GLOBAL source (global_load_lds dest stays linear) + swizzled read offset.
template <int EPI>
__global__ __launch_bounds__(512, 4) void gemm256(
    const unsigned short* __restrict__ A, const unsigned short* __restrict__ Bt,
    const float* __restrict__ b0, const float* __restrict__ b1, const float* __restrict__ b2,
    unsigned short* __restrict__ Qb, unsigned short* __restrict__ Kb, unsigned short* __restrict__ Vb,
    float* __restrict__ Out, int Ncols, int K) {
  __shared__ __align__(16) unsigned short As[2][256][32];
  __shared__ __align__(16) unsigned short Bs[2][256][32];
  const int NT = K >> 5;   // must be even
  const int nb = Ncols >> 8;
  // XCD-aware swizzle (nwg % 8 == 0 for all our launches)
  const int nwg = gridDim.x;
  const int cpx = nwg >> 3;
  const int bid = blockIdx.x;
  const int wg = (bid & 7) * cpx + (bid >> 3);
  const int tm = wg / nb, tn = wg % nb;
  const int rowBase = tm << 8, colBase = tn << 8;
  const int t = threadIdx.x;
  const int lane = t & 63;
  const int w = t >> 6;
  const int li = lane & 15, lg = lane >> 4;
  const int wm = w >> 2, wn = w & 3;
  const int aRow0 = wm * 128;   // wave's A rows within tile
  const int bRow0 = wn * 64;    // wave's Bt rows (= C cols) within tile
  // swizzled k-offset for fragment reads: (row>>1)&3 == (li>>1)&3 for all our rows
  const int koff = ((lg ^ ((li >> 1) & 3)) << 3);

  // staging: 1024 chunks of 16B per matrix per K-tile; 2 chunks/thread.
  // thread's chunk c lands at physical (row=c>>2, pc=c&3); source = logical
  // chunk lc = pc ^ ((row>>1)&3) of that row.
  const int c0 = t, c1 = t + 512;
  const int r0s = c0 >> 2, r1s = c1 >> 2;
  const int l0s = (c0 & 3) ^ ((r0s >> 1) & 3);
  const int l1s = (c1 & 3) ^ ((r1s >> 1) & 3);
  const unsigned short* gA0 = A + (size_t)(rowBase + r0s) * K + l0s * 8;
  const unsigned short* gA1 = A + (size_t)(rowBase + r1s) * K + l1s * 8;
  const unsigned short* gB0 = Bt + (size_t)(colBase + r0s) * K + l0s * 8;
  const unsigned short* gB1 = Bt + (size_t)(colBase + r1s) * K + l1s * 8;

#define STAGE_AB(tile_) do { int b_ = (tile_) & 1; int kt_ = (tile_) << 5;                    \
    __builtin_amdgcn_global_load_lds((gas_cvptr)(gA0 + kt_),                                  \
        (las_vptr)(&As[b_][0][0] + c0 * 8), 16, 0, 0);                                        \
    __builtin_amdgcn_global_load_lds((gas_cvptr)(gA1 + kt_),                                  \
        (las_vptr)(&As[b_][0][0] + c1 * 8), 16, 0, 0);                                        \
    __builtin_amdgcn_global_load_lds((gas_cvptr)(gB0 + kt_),                                  \
        (las_vptr)(&Bs[b_][0][0] + c0 * 8), 16, 0, 0);                                        \
    __builtin_amdgcn_global_load_lds((gas_cvptr)(gB1 + kt_),                                  \
        (las_vptr)(&Bs[b_][0][0] + c1 * 8), 16, 0, 0); } while (0)

  // prologue: stage tiles 0,1; land tile 0 (all waves); read its frags
  STAGE_AB(0); STAGE_AB(1);
  WAITV4;
  BAR();

  f32x4 acc[8][4] = {};
  Frags F0, F1;
  read_frags(F0, &As[0][0][0], &Bs[0][0][0], aRow0, bRow0, li, koff);

  // ITER(tt): CUR = frags(tt) (reads issued last iter); OTH = frags(tt-1) (complete).
#define TILE_ITER(tt_, CUR, OTH) do {                                                         \
    if ((tt_) > 0) {                                                                          \
      __builtin_amdgcn_s_setprio(1);                                                          \
      _Pragma("unroll")                                                                       \
      for (int m = 0; m < 4; m++)                                                             \
        _Pragma("unroll")                                                                     \
        for (int n = 0; n < 4; n++)                                                           \
          acc[4 + m][n] = __builtin_amdgcn_mfma_f32_16x16x32_bf16(OTH.afB[m], OTH.bfr[n],     \
                                                                  acc[4 + m][n], 0, 0, 0);    \
      __builtin_amdgcn_s_setprio(0);                                                          \
      SB();                                                                                   \
    }                                                                                         \
    WAITL0; SB();                                                                             \
    __builtin_amdgcn_s_setprio(1);                                                            \
    _Pragma("unroll")                                                                         \
    for (int m = 0; m < 4; m++)                                                               \
      _Pragma("unroll")                                                                       \
      for (int n = 0; n < 4; n++)                                                             \
        acc[m][n] = __builtin_amdgcn_mfma_f32_16x16x32_bf16(CUR.afA[m], CUR.bfr[n],           \
                                                            acc[m][n], 0, 0, 0);              \
    __builtin_amdgcn_s_setprio(0);                                                            \
    SB();                                                                                     \
    WAITV0;                                                                                   \
    BAR();                                                                                    \
    if ((tt_) + 2 < NT) STAGE_AB((tt_) + 2);                                                  \
    if ((tt_) + 1 < NT)                                                                       \
      read_frags(OTH, &As[((tt_) + 1) & 1][0][0], &Bs[((tt_) + 1) & 1][0][0],                 \
                 aRow0, bRow0, li, koff);                                                     \
  } while (0)

  for (int tt = 0; tt < NT; tt += 2) {
    TILE_ITER(tt, F0, F1);
    TILE_ITER(tt + 1, F1, F0);
  }
  // final MFMA-B of tile NT-1 (CUR of last iter = F1)
  __builtin_amdgcn_s_setprio(1);
#pragma unroll
  for (int m = 0; m < 4; m++)
#pragma unroll
    for (int n = 0; n < 4; n++)
      acc[4 + m][n] = __builtin_amdgcn_mfma_f32_16x16x32_bf16(F1.afB[m], F1.bfr[n],
                                                              acc[4 + m][n], 0, 0, 0);
  __builtin_amdgcn_s_setprio(0);
#undef TILE_ITER
#undef STAGE_AB

  if (EPI == 0) {
    const int part = colBase >> 10;  // 0=Q 1=K 2=V (256 | 1024 so uniform per block)
    const float* __restrict__ bias = (part == 0) ? b0 : (part == 1) ? b1 : b2;
    unsigned short* __restrict__ dst = (part == 0) ? Qb : (part == 1) ? Kb : Vb;
#pragma unroll
    for (int mi = 0; mi < 8; mi++) {
      const int rowb = rowBase + aRow0 + mi * 16 + lg * 4;
#pragma unroll
      for (int r = 0; r < 4; r++) {
        const int row = rowb + r;
        const int b = row >> 6, s = row & 63;
#pragma unroll
        for (int n = 0; n < 4; n++) {
          const int col = colBase + bRow0 + n * 16 + li;
          const int within = col & 1023;
          const int h = within >> 6, dh = within & 63;
          float v = acc[mi][n][r] + bias[within];
          dst[(size_t)((b * 16 + h) * 64 + s) * 64 + dh] = f32_to_bf16(v);
        }
      }
    }
  } else {
#pragma unroll
    for (int mi = 0; mi < 8; mi++) {
      const int rowb = rowBase + aRow0 + mi * 16 + lg * 4;
#pragma unroll
      for (int r = 0; r < 4; r++) {
#pragma unroll
        for (int n = 0; n < 4; n++) {
          const int col = colBase + bRow0 + n * 16 + li;
          float v = acc[mi][n][r] + b0[col];
          v = 0.5f * v * (1.0f + erff(v * 0.70710678118654752f));
          Out[(size_t)(rowb + r) * 1024 + col] = v;
        }
      }
    }
  }
}

// ---------------- attention per (b,h): 64x64, softmax, PV ----------------
__global__ __launch_bounds__(256) void attn(
    const unsigned short* __restrict__ Qb, const unsigned short* __restrict__ Kb,
    const unsigned short* __restrict__ Vb, unsigned short* __restrict__ ctx) {
  __shared__ __align__(16) unsigned short Qs[64][72];
  __shared__ __align__(16) unsigned short Ks[64][72];
  __shared__ __align__(16) unsigned short Vt[64][72];   // transposed: [dh][s]
  __shared__ __align__(16) unsigned short Ps[64][72];
  const int bh = blockIdx.x;
  const int b = bh >> 4, h = bh & 15;
  const int t = threadIdx.x, lane = t & 63, w = t >> 6;
  const int li = lane & 15, lg = lane >> 4;
  const unsigned short* __restrict__ Qg = Qb + (size_t)bh * 4096;
  const unsigned short* __restrict__ Kg = Kb + (size_t)bh * 4096;
  const unsigned short* __restrict__ Vg = Vb + (size_t)bh * 4096;

#pragma unroll
  for (int i = 0; i < 2; i++) {
    const int c = t + i * 256;
    const int row = c >> 3, col8 = (c & 7) * 8;
    *(u16x8*)&Qs[row][col8] = *(const u16x8*)&Qg[row * 64 + col8];
    *(u16x8*)&Ks[row][col8] = *(const u16x8*)&Kg[row * 64 + col8];
    u16x8 v = *(const u16x8*)&Vg[row * 64 + col8];
#pragma unroll
    for (int j = 0; j < 8; j++) Vt[col8 + j][row] = v[j];
  }
  __syncthreads();

  f32x4 sc[4] = {};
#pragma unroll
  for (int ks = 0; ks < 2; ks++) {
    bf16x8 qa = ld_bf16x8(&Qs[w * 16 + li][ks * 32 + lg * 8]);
#pragma unroll
    for (int n = 0; n < 4; n++) {
      bf16x8 kf = ld_bf16x8(&Ks[n * 16 + li][ks * 32 + lg * 8]);
      sc[n] = __builtin_amdgcn_mfma_f32_16x16x32_bf16(qa, kf, sc[n], 0, 0, 0);
    }
  }

#pragma unroll
  for (int r = 0; r < 4; r++) {
    float v0 = sc[0][r] * 0.03125f, v1 = sc[1][r] * 0.03125f;
    float v2 = sc[2][r] * 0.03125f, v3 = sc[3][r] * 0.03125f;
    float mx = fmaxf(fmaxf(v0, v1), fmaxf(v2, v3));
#pragma unroll
    for (int off = 1; off < 16; off <<= 1) mx = fmaxf(mx, __shfl_xor(mx, off, 64));
    float e0 = __expf(v0 - mx), e1 = __expf(v1 - mx);
    float e2 = __expf(v2 - mx), e3 = __expf(v3 - mx);
    float sum = e0 + e1 + e2 + e3;
#pragma unroll
    for (int off = 1; off < 16; off <<= 1) sum += __shfl_xor(sum, off, 64);
    float is = 1.0f / sum;
    const int q = w * 16 + lg * 4 + r;
    Ps[q][0 * 16 + li] = f32_to_bf16(e0 * is);
    Ps[q][1 * 16 + li] = f32_to_bf16(e1 * is);
    Ps[q][2 * 16 + li] = f32_to_bf16(e2 * is);
    Ps[q][3 * 16 + li] = f32_to_bf16(e3 * is);
  }
  __syncthreads();

  f32x4 oc[4] = {};
#pragma unroll
  for (int ks = 0; ks < 2; ks++) {
    bf16x8 pa = ld_bf16x8(&Ps[w * 16 + li][ks * 32 + lg * 8]);
#pragma unroll
    for (int n = 0; n < 4; n++) {
      bf16x8 vf = ld_bf16x8(&Vt[n * 16 + li][ks * 32 + lg * 8]);
      oc[n] = __builtin_amdgcn_mfma_f32_16x16x32_bf16(pa, vf, oc[n], 0, 0, 0);
    }
  }
#pragma unroll
  for (int n = 0; n < 4; n++)
#pragma unroll
    for (int r = 0; r < 4; r++)
      ctx[(size_t)(b * 64 + w * 16 + lg * 4 + r) * 1024 + h * 64 + n * 16 + li] =
          f32_to_bf16(oc[n][r]);
}

extern "C" void kernel_launch(void* const* d_in, const int* in_sizes, int n_in,
                              void* d_out, int out_size, void* d_ws, size_t ws_size,
                              hipStream_t stream) {
  const float* x  = (const float*)d_in[0];
  const float* wq = (const float*)d_in[1];
  const float* bq = (const float*)d_in[2];
  const float* wk = (const float*)d_in[3];
  const float* bk = (const float*)d_in[4];
  const float* wv = (const float*)d_in[5];
  const float* bv = (const float*)d_in[6];
  const float* wo = (const float*)d_in[7];
  const float* bo = (const float*)d_in[8];
  float* out = (float*)d_out;

  const int D = 1024;
  const int M = in_sizes[0] / D;  // B*S = 32768

  char* ws = (char*)d_ws;
  unsigned short* xb    = (unsigned short*)ws;
  unsigned short* wqkvT = (unsigned short*)(ws + (size_t)M * 1024 * 2);
  unsigned short* woT   = wqkvT + (size_t)3 * 1024 * 1024;
  unsigned short* Qb    = woT + (size_t)1024 * 1024;
  unsigned short* Kb    = Qb + (size_t)M * 1024;
  unsigned short* Vb    = Kb + (size_t)M * 1024;
  unsigned short* ctx   = xb;  // reuse: x no longer needed after QKV GEMM

  cvt_x<<<2048, 256, 0, stream>>>(x, xb, M * D / 4);
  cvt_w<<<dim3(16, 16, 4), 256, 0, stream>>>(wq, wk, wv, wo, wqkvT, woT);
  gemm256<0><<<(M / 256) * (3072 / 256), 512, 0, stream>>>(
      xb, wqkvT, bq, bk, bv, Qb, Kb, Vb, nullptr, 3072, 1024);
  attn<<<(M / 64) * 16, 256, 0, stream>>>(Qb, Kb, Vb, ctx);
  gemm256<1><<<(M / 256) * (1024 / 256), 512, 0, stream>>>(
      ctx, woT, bo, nullptr, nullptr, nullptr, nullptr, nullptr, out, 1024, 1024);
}

// Round 7
// 428.381 us; speedup vs baseline: 10.8763x; 10.8763x over previous
//
#include <hip/hip_runtime.h>
#include <cstdint>
#include <math.h>

typedef float f32x4 __attribute__((ext_vector_type(4)));
typedef __bf16 bf16x8 __attribute__((ext_vector_type(8)));
typedef unsigned short u16x8 __attribute__((ext_vector_type(8)));
typedef unsigned short u16x4 __attribute__((ext_vector_type(4)));

typedef __attribute__((address_space(1))) const void* gas_cvptr;
typedef __attribute__((address_space(3))) void* las_vptr;

#define WAITV6 asm volatile("s_waitcnt vmcnt(6)" ::: "memory")
#define WAITV0 asm volatile("s_waitcnt vmcnt(0)" ::: "memory")
#define WAITL4 asm volatile("s_waitcnt lgkmcnt(4)" ::: "memory")
#define WAITL0 asm volatile("s_waitcnt lgkmcnt(0)" ::: "memory")
#define SB()   __builtin_amdgcn_sched_barrier(0)
#define BAR()  __builtin_amdgcn_s_barrier()

__device__ __forceinline__ unsigned short f32_to_bf16(float f) {
  uint32_t u = __builtin_bit_cast(uint32_t, f);
  u += 0x7FFFu + ((u >> 16) & 1u);   // round-to-nearest-even
  return (unsigned short)(u >> 16);
}

__device__ __forceinline__ bf16x8 ld_bf16x8(const unsigned short* p) {
  return __builtin_bit_cast(bf16x8, *(const u16x8*)p);
}

// ---------------- convert x: f32 -> bf16 ----------------
__global__ void cvt_x(const float* __restrict__ x, unsigned short* __restrict__ xb, int n4) {
  int stride = gridDim.x * blockDim.x;
  for (int i = blockIdx.x * blockDim.x + threadIdx.x; i < n4; i += stride) {
    float4 v = ((const float4*)x)[i];
    u16x4 o = { f32_to_bf16(v.x), f32_to_bf16(v.y), f32_to_bf16(v.z), f32_to_bf16(v.w) };
    ((u16x4*)xb)[i] = o;
  }
}

// ------------- transpose weights [K][N] f32 -> [N][K] bf16 -------------
__global__ void cvt_w(const float* __restrict__ wq, const float* __restrict__ wk,
                      const float* __restrict__ wv, const float* __restrict__ wo,
                      unsigned short* __restrict__ wqkvT, unsigned short* __restrict__ woT) {
  const int z = blockIdx.z;
  const float* __restrict__ w = (z == 0) ? wq : (z == 1) ? wk : (z == 2) ? wv : wo;
  unsigned short* __restrict__ out = (z < 3) ? (wqkvT + (size_t)z * 1024 * 1024) : woT;
  __shared__ float tile[64][65];
  const int r0 = blockIdx.y * 64;  // k dim
  const int c0 = blockIdx.x * 64;  // n dim
  const int t = threadIdx.x;
#pragma unroll
  for (int i = 0; i < 4; i++) {
    int row = (t >> 4) + i * 16;
    int col = (t & 15) * 4;
    float4 v = *(const float4*)&w[(size_t)(r0 + row) * 1024 + c0 + col];
    tile[row][col] = v.x; tile[row][col + 1] = v.y;
    tile[row][col + 2] = v.z; tile[row][col + 3] = v.w;
  }
  __syncthreads();
#pragma unroll
  for (int i = 0; i < 2; i++) {
    int nr = (t >> 3) + i * 32;
    int kc = (t & 7) * 8;
    u16x8 o;
#pragma unroll
    for (int j = 0; j < 8; j++) o[j] = f32_to_bf16(tile[kc + j][nr]);
    *(u16x8*)&out[(size_t)(c0 + nr) * 1024 + r0 + kc] = o;
  }
}

// ============ 128x256-tile GEMM, 4-wave blocks, 2 blocks/CU ============
// C = A[M][K] @ Bt[N][K]^T. 256 threads = 4 waves, each owns 128 rows x 64 cols
// (8 m-frags x 4 n-frags, acc 128 AGPR). BK=32; 3 LDS buffers (72 KB) so TWO
// blocks co-reside per CU: independent barrier domains fill each other's
// vmcnt/barrier stalls (round-5: 1400 cyc/tile exposed stall at 1 block/CU).
// Round-6 lesson: never cap reg budget below acc footprint (launch_bounds(512,4)
// -> 128-reg cap vs 250 needed -> total spill). Here ~208 regs <= 256 cap.
// Per tile tt: STAGE(tt+2)->buf[(tt+2)%3] (WAR: that buffer's reads drained at
// tile tt-1's lgkm0 + barrier) | 12 ds_reads(tt) | WAITL4 MFMA-A | WAITL0 MFMA-B
// | WAITV6 (stage tt+1 landed, tt+2 in flight) | BAR.
// LDS bank-conflict fix: physical 16B-chunk pc = lc ^ ((row>>1)&3), pre-swizzled
// GLOBAL source (global_load_lds dest stays linear) + swizzled read offset.
template <int EPI>
__global__ __launch_bounds__(256, 2) void gemm256(
    const unsigned short* __restrict__ A, const unsigned short* __restrict__ Bt,
    const float* __restrict__ b0, const float* __restrict__ b1, const float* __restrict__ b2,
    unsigned short* __restrict__ Qb, unsigned short* __restrict__ Kb, unsigned short* __restrict__ Vb,
    float* __restrict__ Out, int Ncols, int K) {
  __shared__ __align__(16) unsigned short As[3][128][32];
  __shared__ __align__(16) unsigned short Bs[3][256][32];
  const int NT = K >> 5;
  const int nb = Ncols >> 8;
  // XCD-aware swizzle (nwg % 8 == 0 for all our launches)
  const int nwg = gridDim.x;
  const int cpx = nwg >> 3;
  const int bid = blockIdx.x;
  const int wg = (bid & 7) * cpx + (bid >> 3);
  const int tm = wg / nb, tn = wg % nb;
  const int rowBase = tm << 7, colBase = tn << 8;
  const int t = threadIdx.x;
  const int lane = t & 63;
  const int w = t >> 6;             // 4 waves
  const int li = lane & 15, lg = lane >> 4;
  const int bRow0 = w << 6;         // wave's Bt rows (= C cols) within tile
  // swizzled k-offset for fragment reads: (row>>1)&3 == (li>>1)&3 for all our rows
  const int koff = ((lg ^ ((li >> 1) & 3)) << 3);

  // staging: A 512 chunks (2/thread), B 1024 chunks (4/thread), 16B each.
  // chunk c -> physical (row=c>>2, pc=c&3); global source = logical chunk
  // lc = pc ^ ((row>>1)&3) of that row.
  const int cA0 = t, cA1 = t + 256;
  const int cB0 = t, cB1 = t + 256, cB2 = t + 512, cB3 = t + 768;
#define SRC(PTR, base_, c_) (PTR + (size_t)(base_ + ((c_) >> 2)) * K + \
                             (((c_) & 3) ^ ((((c_) >> 2) >> 1) & 3)) * 8)
  const unsigned short* gA0 = SRC(A, rowBase, cA0);
  const unsigned short* gA1 = SRC(A, rowBase, cA1);
  const unsigned short* gB0 = SRC(Bt, colBase, cB0);
  const unsigned short* gB1 = SRC(Bt, colBase, cB1);
  const unsigned short* gB2 = SRC(Bt, colBase, cB2);
  const unsigned short* gB3 = SRC(Bt, colBase, cB3);
#undef SRC

#define STAGE_AB(tile_) do { int b_ = (tile_) % 3; int kt_ = (tile_) << 5;                    \
    __builtin_amdgcn_global_load_lds((gas_cvptr)(gA0 + kt_),                                  \
        (las_vptr)(&As[b_][0][0] + cA0 * 8), 16, 0, 0);                                       \
    __builtin_amdgcn_global_load_lds((gas_cvptr)(gA1 + kt_),                                  \
        (las_vptr)(&As[b_][0][0] + cA1 * 8), 16, 0, 0);                                       \
    __builtin_amdgcn_global_load_lds((gas_cvptr)(gB0 + kt_),                                  \
        (las_vptr)(&Bs[b_][0][0] + cB0 * 8), 16, 0, 0);                                       \
    __builtin_amdgcn_global_load_lds((gas_cvptr)(gB1 + kt_),                                  \
        (las_vptr)(&Bs[b_][0][0] + cB1 * 8), 16, 0, 0);                                       \
    __builtin_amdgcn_global_load_lds((gas_cvptr)(gB2 + kt_),                                  \
        (las_vptr)(&Bs[b_][0][0] + cB2 * 8), 16, 0, 0);                                       \
    __builtin_amdgcn_global_load_lds((gas_cvptr)(gB3 + kt_),                                  \
        (las_vptr)(&Bs[b_][0][0] + cB3 * 8), 16, 0, 0); } while (0)

  // prologue: stage tiles 0,1; land tile 0 in every wave
  STAGE_AB(0); STAGE_AB(1);
  WAITV6;
  BAR();

  f32x4 acc[8][4] = {};

  for (int tt = 0; tt < NT; ++tt) {
    if (tt + 2 < NT) STAGE_AB(tt + 2);
    const unsigned short* ab = &As[tt % 3][0][0];
    const unsigned short* bb = &Bs[tt % 3][0][0];
    bf16x8 afA[4], bfr[4], afB[4];
#pragma unroll
    for (int m = 0; m < 4; m++) afA[m] = ld_bf16x8(ab + (m * 16 + li) * 32 + koff);
#pragma unroll
    for (int n = 0; n < 4; n++) bfr[n] = ld_bf16x8(bb + (bRow0 + n * 16 + li) * 32 + koff);
#pragma unroll
    for (int m = 0; m < 4; m++) afB[m] = ld_bf16x8(ab + (64 + m * 16 + li) * 32 + koff);
    WAITL4;             // afA,bfr landed; afB in flight
    SB();
    __builtin_amdgcn_s_setprio(1);
#pragma unroll
    for (int m = 0; m < 4; m++)
#pragma unroll
      for (int n = 0; n < 4; n++)
        acc[m][n] = __builtin_amdgcn_mfma_f32_16x16x32_bf16(afA[m], bfr[n], acc[m][n], 0, 0, 0);
    __builtin_amdgcn_s_setprio(0);
    SB();
    WAITL0;             // afB landed
    SB();
    __builtin_amdgcn_s_setprio(1);
#pragma unroll
    for (int m = 0; m < 4; m++)
#pragma unroll
      for (int n = 0; n < 4; n++)
        acc[4 + m][n] = __builtin_amdgcn_mfma_f32_16x16x32_bf16(afB[m], bfr[n], acc[4 + m][n], 0, 0, 0);
    __builtin_amdgcn_s_setprio(0);
    // stage(tt+1) must be landed before next tile's reads; stage(tt+2) stays in flight
    if (tt < NT - 2) WAITV6; else WAITV0;
    BAR();
  }
#undef STAGE_AB

  if (EPI == 0) {
    const int part = colBase >> 10;  // 0=Q 1=K 2=V (256 | 1024 so uniform per block)
    const float* __restrict__ bias = (part == 0) ? b0 : (part == 1) ? b1 : b2;
    unsigned short* __restrict__ dst = (part == 0) ? Qb : (part == 1) ? Kb : Vb;
#pragma unroll
    for (int mi = 0; mi < 8; mi++) {
      const int rowb = rowBase + mi * 16 + lg * 4;
#pragma unroll
      for (int r = 0; r < 4; r++) {
        const int row = rowb + r;
        const int b = row >> 6, s = row & 63;
#pragma unroll
        for (int n = 0; n < 4; n++) {
          const int col = colBase + bRow0 + n * 16 + li;
          const int within = col & 1023;
          const int h = within >> 6, dh = within & 63;
          float v = acc[mi][n][r] + bias[within];
          dst[(size_t)((b * 16 + h) * 64 + s) * 64 + dh] = f32_to_bf16(v);
        }
      }
    }
  } else {
#pragma unroll
    for (int mi = 0; mi < 8; mi++) {
      const int rowb = rowBase + mi * 16 + lg * 4;
#pragma unroll
      for (int r = 0; r < 4; r++) {
#pragma unroll
        for (int n = 0; n < 4; n++) {
          const int col = colBase + bRow0 + n * 16 + li;
          float v = acc[mi][n][r] + b0[col];
          v = 0.5f * v * (1.0f + erff(v * 0.70710678118654752f));
          Out[(size_t)(rowb + r) * 1024 + col] = v;
        }
      }
    }
  }
}

// ---------------- attention per (b,h): 64x64, softmax, PV ----------------
__global__ __launch_bounds__(256) void attn(
    const unsigned short* __restrict__ Qb, const unsigned short* __restrict__ Kb,
    const unsigned short* __restrict__ Vb, unsigned short* __restrict__ ctx) {
  __shared__ __align__(16) unsigned short Qs[64][72];
  __shared__ __align__(16) unsigned short Ks[64][72];
  __shared__ __align__(16) unsigned short Vt[64][72];   // transposed: [dh][s]
  __shared__ __align__(16) unsigned short Ps[64][72];
  const int bh = blockIdx.x;
  const int b = bh >> 4, h = bh & 15;
  const int t = threadIdx.x, lane = t & 63, w = t >> 6;
  const int li = lane & 15, lg = lane >> 4;
  const unsigned short* __restrict__ Qg = Qb + (size_t)bh * 4096;
  const unsigned short* __restrict__ Kg = Kb + (size_t)bh * 4096;
  const unsigned short* __restrict__ Vg = Vb + (size_t)bh * 4096;

#pragma unroll
  for (int i = 0; i < 2; i++) {
    const int c = t + i * 256;
    const int row = c >> 3, col8 = (c & 7) * 8;
    *(u16x8*)&Qs[row][col8] = *(const u16x8*)&Qg[row * 64 + col8];
    *(u16x8*)&Ks[row][col8] = *(const u16x8*)&Kg[row * 64 + col8];
    u16x8 v = *(const u16x8*)&Vg[row * 64 + col8];
#pragma unroll
    for (int j = 0; j < 8; j++) Vt[col8 + j][row] = v[j];
  }
  __syncthreads();

  f32x4 sc[4] = {};
#pragma unroll
  for (int ks = 0; ks < 2; ks++) {
    bf16x8 qa = ld_bf16x8(&Qs[w * 16 + li][ks * 32 + lg * 8]);
#pragma unroll
    for (int n = 0; n < 4; n++) {
      bf16x8 kf = ld_bf16x8(&Ks[n * 16 + li][ks * 32 + lg * 8]);
      sc[n] = __builtin_amdgcn_mfma_f32_16x16x32_bf16(qa, kf, sc[n], 0, 0, 0);
    }
  }

#pragma unroll
  for (int r = 0; r < 4; r++) {
    float v0 = sc[0][r] * 0.03125f, v1 = sc[1][r] * 0.03125f;
    float v2 = sc[2][r] * 0.03125f, v3 = sc[3][r] * 0.03125f;
    float mx = fmaxf(fmaxf(v0, v1), fmaxf(v2, v3));
#pragma unroll
    for (int off = 1; off < 16; off <<= 1) mx = fmaxf(mx, __shfl_xor(mx, off, 64));
    float e0 = __expf(v0 - mx), e1 = __expf(v1 - mx);
    float e2 = __expf(v2 - mx), e3 = __expf(v3 - mx);
    float sum = e0 + e1 + e2 + e3;
#pragma unroll
    for (int off = 1; off < 16; off <<= 1) sum += __shfl_xor(sum, off, 64);
    float is = 1.0f / sum;
    const int q = w * 16 + lg * 4 + r;
    Ps[q][0 * 16 + li] = f32_to_bf16(e0 * is);
    Ps[q][1 * 16 + li] = f32_to_bf16(e1 * is);
    Ps[q][2 * 16 + li] = f32_to_bf16(e2 * is);
    Ps[q][3 * 16 + li] = f32_to_bf16(e3 * is);
  }
  __syncthreads();

  f32x4 oc[4] = {};
#pragma unroll
  for (int ks = 0; ks < 2; ks++) {
    bf16x8 pa = ld_bf16x8(&Ps[w * 16 + li][ks * 32 + lg * 8]);
#pragma unroll
    for (int n = 0; n < 4; n++) {
      bf16x8 vf = ld_bf16x8(&Vt[n * 16 + li][ks * 32 + lg * 8]);
      oc[n] = __builtin_amdgcn_mfma_f32_16x16x32_bf16(pa, vf, oc[n], 0, 0, 0);
    }
  }
#pragma unroll
  for (int n = 0; n < 4; n++)
#pragma unroll
    for (int r = 0; r < 4; r++)
      ctx[(size_t)(b * 64 + w * 16 + lg * 4 + r) * 1024 + h * 64 + n * 16 + li] =
          f32_to_bf16(oc[n][r]);
}

extern "C" void kernel_launch(void* const* d_in, const int* in_sizes, int n_in,
                              void* d_out, int out_size, void* d_ws, size_t ws_size,
                              hipStream_t stream) {
  const float* x  = (const float*)d_in[0];
  const float* wq = (const float*)d_in[1];
  const float* bq = (const float*)d_in[2];
  const float* wk = (const float*)d_in[3];
  const float* bk = (const float*)d_in[4];
  const float* wv = (const float*)d_in[5];
  const float* bv = (const float*)d_in[6];
  const float* wo = (const float*)d_in[7];
  const float* bo = (const float*)d_in[8];
  float* out = (float*)d_out;

  const int D = 1024;
  const int M = in_sizes[0] / D;  // B*S = 32768

  char* ws = (char*)d_ws;
  unsigned short* xb    = (unsigned short*)ws;
  unsigned short* wqkvT = (unsigned short*)(ws + (size_t)M * 1024 * 2);
  unsigned short* woT   = wqkvT + (size_t)3 * 1024 * 1024;
  unsigned short* Qb    = woT + (size_t)1024 * 1024;
  unsigned short* Kb    = Qb + (size_t)M * 1024;
  unsigned short* Vb    = Kb + (size_t)M * 1024;
  unsigned short* ctx   = xb;  // reuse: x no longer needed after QKV GEMM

  cvt_x<<<2048, 256, 0, stream>>>(x, xb, M * D / 4);
  cvt_w<<<dim3(16, 16, 4), 256, 0, stream>>>(wq, wk, wv, wo, wqkvT, woT);
  gemm256<0><<<(M / 128) * (3072 / 256), 256, 0, stream>>>(
      xb, wqkvT, bq, bk, bv, Qb, Kb, Vb, nullptr, 3072, 1024);
  attn<<<(M / 64) * 16, 256, 0, stream>>>(Qb, Kb, Vb, ctx);
  gemm256<1><<<(M / 128) * (1024 / 256), 256, 0, stream>>>(
      ctx, woT, bo, nullptr, nullptr, nullptr, nullptr, nullptr, out, 1024, 1024);
}

// Round 8
// 422.105 us; speedup vs baseline: 11.0381x; 1.0149x over previous
//
#include <hip/hip_runtime.h>
#include <cstdint>
#include <math.h>

typedef float f32x4 __attribute__((ext_vector_type(4)));
typedef __bf16 bf16x8 __attribute__((ext_vector_type(8)));
typedef unsigned short u16x8 __attribute__((ext_vector_type(8)));
typedef unsigned short u16x4 __attribute__((ext_vector_type(4)));

typedef __attribute__((address_space(1))) const void* gas_cvptr;
typedef __attribute__((address_space(3))) void* las_vptr;

#define WAITV2 asm volatile("s_waitcnt vmcnt(2)" ::: "memory")
#define WAITV0 asm volatile("s_waitcnt vmcnt(0)" ::: "memory")
#define WAITL0 asm volatile("s_waitcnt lgkmcnt(0)" ::: "memory")
#define SB()   __builtin_amdgcn_sched_barrier(0)
#define BAR()  __builtin_amdgcn_s_barrier()
#define PRIO1() __builtin_amdgcn_s_setprio(1)
#define PRIO0() __builtin_amdgcn_s_setprio(0)

__device__ __forceinline__ unsigned short f32_to_bf16(float f) {
  uint32_t u = __builtin_bit_cast(uint32_t, f);
  u += 0x7FFFu + ((u >> 16) & 1u);   // round-to-nearest-even
  return (unsigned short)(u >> 16);
}

__device__ __forceinline__ bf16x8 ld_bf16x8(const unsigned short* p) {
  return __builtin_bit_cast(bf16x8, *(const u16x8*)p);
}

// ---------------- convert x: f32 -> bf16 ----------------
__global__ void cvt_x(const float* __restrict__ x, unsigned short* __restrict__ xb, int n4) {
  int stride = gridDim.x * blockDim.x;
  for (int i = blockIdx.x * blockDim.x + threadIdx.x; i < n4; i += stride) {
    float4 v = ((const float4*)x)[i];
    u16x4 o = { f32_to_bf16(v.x), f32_to_bf16(v.y), f32_to_bf16(v.z), f32_to_bf16(v.w) };
    ((u16x4*)xb)[i] = o;
  }
}

// ------------- transpose weights [K][N] f32 -> [N][K] bf16 -------------
__global__ void cvt_w(const float* __restrict__ wq, const float* __restrict__ wk,
                      const float* __restrict__ wv, const float* __restrict__ wo,
                      unsigned short* __restrict__ wqkvT, unsigned short* __restrict__ woT) {
  const int z = blockIdx.z;
  const float* __restrict__ w = (z == 0) ? wq : (z == 1) ? wk : (z == 2) ? wv : wo;
  unsigned short* __restrict__ out = (z < 3) ? (wqkvT + (size_t)z * 1024 * 1024) : woT;
  __shared__ float tile[64][65];
  const int r0 = blockIdx.y * 64;  // k dim
  const int c0 = blockIdx.x * 64;  // n dim
  const int t = threadIdx.x;
#pragma unroll
  for (int i = 0; i < 4; i++) {
    int row = (t >> 4) + i * 16;
    int col = (t & 15) * 4;
    float4 v = *(const float4*)&w[(size_t)(r0 + row) * 1024 + c0 + col];
    tile[row][col] = v.x; tile[row][col + 1] = v.y;
    tile[row][col + 2] = v.z; tile[row][col + 3] = v.w;
  }
  __syncthreads();
#pragma unroll
  for (int i = 0; i < 2; i++) {
    int nr = (t >> 3) + i * 32;
    int kc = (t & 7) * 8;
    u16x8 o;
#pragma unroll
    for (int j = 0; j < 8; j++) o[j] = f32_to_bf16(tile[kc + j][nr]);
    *(u16x8*)&out[(size_t)(c0 + nr) * 1024 + r0 + kc] = o;
  }
}

// ============== 256x256 8-phase GEMM (m201 port): C = A @ Bt^T ==============
// 512 thr = 8 waves (2 wm x 4 wn), wave tile 128x64, BK=64, 2 dbuf (128 KB LDS).
// Per K-tile: 4 phases = C-quadrants Q00,Q01,Q11,Q10; each phase:
//   {ds_read subtile | stage 1 half-tile | [vmcnt] | BAR | lgkm0 | 16 MFMA | BAR}.
// Reads/phase: 12 (a0+b0), 4 (b1), 8 (a1), 0 (regs). Counted vmcnt(2) once per
// tile at ph4 BEFORE the leading barrier (confirm -> barrier -> read, cross-wave
// safe). Stages: ph1 A1h(tt+1), ph2 B0h(tt+1), ph3 B1h(tt+1) -> buf^1 (last read
// tile tt-1, drained); ph4 A0h(tt+2) -> current buf rows 0..127 (last read ph3).
// Swizzle (128B rows): physical 16B-chunk pc = c ^ (row&7); pre-swizzled global
// source (gload_lds dest linear) + swizzled read offset -> frag reads 2-way max.
template <int EPI>
__global__ __launch_bounds__(512, 2) void gemm8p(
    const unsigned short* __restrict__ A, const unsigned short* __restrict__ Bt,
    const float* __restrict__ b0p, const float* __restrict__ b1p, const float* __restrict__ b2p,
    unsigned short* __restrict__ Qb, unsigned short* __restrict__ Kb, unsigned short* __restrict__ Vb,
    float* __restrict__ Out, int Ncols, int K) {
  __shared__ __align__(16) unsigned short As[2][256][64];
  __shared__ __align__(16) unsigned short Bs[2][256][64];
  const int NT = K >> 6;          // K-tiles of 64 (NT=16 here)
  const int nb = Ncols >> 8;
  const int nwg = gridDim.x;      // XCD swizzle (nwg % 8 == 0)
  const int cpx = nwg >> 3;
  const int bid = blockIdx.x;
  const int wg = (bid & 7) * cpx + (bid >> 3);
  const int tm = wg / nb, tn = wg % nb;
  const int rowBase = tm << 8, colBase = tn << 8;
  const int t = threadIdx.x;
  const int lane = t & 63;
  const int w = t >> 6;
  const int li = lane & 15, lg = lane >> 4;
  const int wm = w >> 2, wn = w & 3;
  const int aBase = wm << 7;      // wave's A rows (one A-half)
  const int bBase = wn << 6;      // wave's Bt rows = C cols
  // swizzled element offsets for the two k-slots of a fragment row (row&7 == li&7)
  const int pcb0 = (lg ^ (li & 7)) << 3;
  const int pcb1 = ((4 + lg) ^ (li & 7)) << 3;

  // staging: half-tile = 128 rows x 8 chunks(16B) = 1024 chunks; 2 chunks/thread.
  // chunk c -> physical (row=c>>3, pc=c&7); source logical chunk = pc ^ (row&7).
  const int c0 = t, c1 = t + 512;
  const int r0s = c0 >> 3, r1s = c1 >> 3;
  const size_t off0 = (size_t)r0s * K + (((c0 & 7) ^ (r0s & 7)) << 3);
  const size_t off1 = (size_t)r1s * K + (((c1 & 7) ^ (r1s & 7)) << 3);
  const unsigned short* srcA = A + (size_t)rowBase * K;
  const unsigned short* srcB = Bt + (size_t)colBase * K;

#define GLDS(s_, d_) __builtin_amdgcn_global_load_lds((gas_cvptr)(s_), (las_vptr)(d_), 16, 0, 0)
#define STAGE_A(b_, h_, t_) do {                                                   \
    const unsigned short* s_ = srcA + (size_t)(h_) * 128 * K + ((t_) << 6);        \
    unsigned short* d_ = &As[b_][(h_) * 128][0];                                   \
    GLDS(s_ + off0, d_ + c0 * 8); GLDS(s_ + off1, d_ + c1 * 8); } while (0)
#define STAGE_B(b_, h_, t_) do {                                                   \
    const unsigned short* s_ = srcB + (size_t)(h_) * 128 * K + ((t_) << 6);        \
    unsigned short* d_ = &Bs[b_][(h_) * 128][0];                                   \
    GLDS(s_ + off0, d_ + c0 * 8); GLDS(s_ + off1, d_ + c1 * 8); } while (0)

  // prologue: tile0's 4 halves + A0h(1); confirm tile0 (vmcnt(2)), barrier.
  STAGE_A(0, 0, 0); STAGE_A(0, 1, 0); STAGE_B(0, 0, 0); STAGE_B(0, 1, 0);
  STAGE_A(1, 0, 1);
  WAITV2;
  BAR();

  f32x4 acc[8][4] = {};
  bf16x8 a0[8], a1[8], b0f[4], b1f[4];

  for (int tt = 0; tt < NT; ++tt) {
    const int buf = tt & 1;
    const unsigned short* ab = &As[buf][0][0];
    const unsigned short* bb = &Bs[buf][0][0];
    // ---------------- phase 1: read a0(8)+b0(4); stage A1h(tt+1); Q00 ----------------
#pragma unroll
    for (int m = 0; m < 4; m++) {
      const unsigned short* rp = ab + (aBase + m * 16 + li) * 64;
      a0[m * 2] = ld_bf16x8(rp + pcb0);
      a0[m * 2 + 1] = ld_bf16x8(rp + pcb1);
    }
#pragma unroll
    for (int n = 0; n < 2; n++) {
      const unsigned short* rp = bb + (bBase + n * 16 + li) * 64;
      b0f[n * 2] = ld_bf16x8(rp + pcb0);
      b0f[n * 2 + 1] = ld_bf16x8(rp + pcb1);
    }
    if (tt + 1 < NT) STAGE_A(buf ^ 1, 1, tt + 1);
    BAR();
    WAITL0; SB();
    PRIO1();
#pragma unroll
    for (int ks = 0; ks < 2; ks++)
#pragma unroll
      for (int m = 0; m < 4; m++)
#pragma unroll
        for (int n = 0; n < 2; n++)
          acc[m][n] = __builtin_amdgcn_mfma_f32_16x16x32_bf16(a0[m * 2 + ks], b0f[n * 2 + ks],
                                                              acc[m][n], 0, 0, 0);
    PRIO0();
    BAR();
    // ---------------- phase 2: read b1(4); stage B0h(tt+1); Q01 ----------------
#pragma unroll
    for (int n = 0; n < 2; n++) {
      const unsigned short* rp = bb + (bBase + 32 + n * 16 + li) * 64;
      b1f[n * 2] = ld_bf16x8(rp + pcb0);
      b1f[n * 2 + 1] = ld_bf16x8(rp + pcb1);
    }
    if (tt + 1 < NT) STAGE_B(buf ^ 1, 0, tt + 1);
    BAR();
    WAITL0; SB();
    PRIO1();
#pragma unroll
    for (int ks = 0; ks < 2; ks++)
#pragma unroll
      for (int m = 0; m < 4; m++)
#pragma unroll
        for (int n = 0; n < 2; n++)
          acc[m][2 + n] = __builtin_amdgcn_mfma_f32_16x16x32_bf16(a0[m * 2 + ks], b1f[n * 2 + ks],
                                                                  acc[m][2 + n], 0, 0, 0);
    PRIO0();
    BAR();
    // ---------------- phase 3: read a1(8); stage B1h(tt+1); Q11 ----------------
#pragma unroll
    for (int m = 0; m < 4; m++) {
      const unsigned short* rp = ab + (aBase + 64 + m * 16 + li) * 64;
      a1[m * 2] = ld_bf16x8(rp + pcb0);
      a1[m * 2 + 1] = ld_bf16x8(rp + pcb1);
    }
    if (tt + 1 < NT) STAGE_B(buf ^ 1, 1, tt + 1);
    BAR();
    WAITL0; SB();
    PRIO1();
#pragma unroll
    for (int ks = 0; ks < 2; ks++)
#pragma unroll
      for (int m = 0; m < 4; m++)
#pragma unroll
        for (int n = 0; n < 2; n++)
          acc[4 + m][2 + n] = __builtin_amdgcn_mfma_f32_16x16x32_bf16(a1[m * 2 + ks], b1f[n * 2 + ks],
                                                                      acc[4 + m][2 + n], 0, 0, 0);
    PRIO0();
    BAR();
    // -------- phase 4: stage A0h(tt+2) -> current buf; confirm tile tt+1; Q10 --------
    if (tt + 2 < NT) STAGE_A(buf, 0, tt + 2);
    if (tt >= NT - 2) { WAITV0; } else { WAITV2; }   // confirm all halves of tt+1
    BAR();
    PRIO1();
#pragma unroll
    for (int ks = 0; ks < 2; ks++)
#pragma unroll
      for (int m = 0; m < 4; m++)
#pragma unroll
        for (int n = 0; n < 2; n++)
          acc[4 + m][n] = __builtin_amdgcn_mfma_f32_16x16x32_bf16(a1[m * 2 + ks], b0f[n * 2 + ks],
                                                                  acc[4 + m][n], 0, 0, 0);
    PRIO0();
    BAR();
  }
#undef STAGE_A
#undef STAGE_B
#undef GLDS

  if (EPI == 0) {
    const int part = colBase >> 10;  // 0=Q 1=K 2=V (256 | 1024 so uniform per block)
    const float* __restrict__ bias = (part == 0) ? b0p : (part == 1) ? b1p : b2p;
    unsigned short* __restrict__ dst = (part == 0) ? Qb : (part == 1) ? Kb : Vb;
#pragma unroll
    for (int mi = 0; mi < 8; mi++) {
      const int rowb = rowBase + aBase + mi * 16 + lg * 4;
#pragma unroll
      for (int r = 0; r < 4; r++) {
        const int row = rowb + r;
        const int b = row >> 6, s = row & 63;
#pragma unroll
        for (int n = 0; n < 4; n++) {
          const int col = colBase + bBase + n * 16 + li;
          const int within = col & 1023;
          const int h = within >> 6, dh = within & 63;
          float v = acc[mi][n][r] + bias[within];
          dst[(size_t)((b * 16 + h) * 64 + s) * 64 + dh] = f32_to_bf16(v);
        }
      }
    }
  } else {
#pragma unroll
    for (int mi = 0; mi < 8; mi++) {
      const int rowb = rowBase + aBase + mi * 16 + lg * 4;
#pragma unroll
      for (int r = 0; r < 4; r++) {
#pragma unroll
        for (int n = 0; n < 4; n++) {
          const int col = colBase + bBase + n * 16 + li;
          float v = acc[mi][n][r] + b0p[col];
          v = 0.5f * v * (1.0f + erff(v * 0.70710678118654752f));
          Out[(size_t)(rowb + r) * 1024 + col] = v;
        }
      }
    }
  }
}

// ---------------- attention per (b,h): 64x64, softmax, PV ----------------
__global__ __launch_bounds__(256) void attn(
    const unsigned short* __restrict__ Qb, const unsigned short* __restrict__ Kb,
    const unsigned short* __restrict__ Vb, unsigned short* __restrict__ ctx) {
  __shared__ __align__(16) unsigned short Qs[64][72];
  __shared__ __align__(16) unsigned short Ks[64][72];
  __shared__ __align__(16) unsigned short Vt[64][72];   // transposed: [dh][s]
  __shared__ __align__(16) unsigned short Ps[64][72];
  const int bh = blockIdx.x;
  const int b = bh >> 4, h = bh & 15;
  const int t = threadIdx.x, lane = t & 63, w = t >> 6;
  const int li = lane & 15, lg = lane >> 4;
  const unsigned short* __restrict__ Qg = Qb + (size_t)bh * 4096;
  const unsigned short* __restrict__ Kg = Kb + (size_t)bh * 4096;
  const unsigned short* __restrict__ Vg = Vb + (size_t)bh * 4096;

#pragma unroll
  for (int i = 0; i < 2; i++) {
    const int c = t + i * 256;
    const int row = c >> 3, col8 = (c & 7) * 8;
    *(u16x8*)&Qs[row][col8] = *(const u16x8*)&Qg[row * 64 + col8];
    *(u16x8*)&Ks[row][col8] = *(const u16x8*)&Kg[row * 64 + col8];
    u16x8 v = *(const u16x8*)&Vg[row * 64 + col8];
#pragma unroll
    for (int j = 0; j < 8; j++) Vt[col8 + j][row] = v[j];
  }
  __syncthreads();

  f32x4 sc[4] = {};
#pragma unroll
  for (int ks = 0; ks < 2; ks++) {
    bf16x8 qa = ld_bf16x8(&Qs[w * 16 + li][ks * 32 + lg * 8]);
#pragma unroll
    for (int n = 0; n < 4; n++) {
      bf16x8 kf = ld_bf16x8(&Ks[n * 16 + li][ks * 32 + lg * 8]);
      sc[n] = __builtin_amdgcn_mfma_f32_16x16x32_bf16(qa, kf, sc[n], 0, 0, 0);
    }
  }

#pragma unroll
  for (int r = 0; r < 4; r++) {
    float v0 = sc[0][r] * 0.03125f, v1 = sc[1][r] * 0.03125f;
    float v2 = sc[2][r] * 0.03125f, v3 = sc[3][r] * 0.03125f;
    float mx = fmaxf(fmaxf(v0, v1), fmaxf(v2, v3));
#pragma unroll
    for (int off = 1; off < 16; off <<= 1) mx = fmaxf(mx, __shfl_xor(mx, off, 64));
    float e0 = __expf(v0 - mx), e1 = __expf(v1 - mx);
    float e2 = __expf(v2 - mx), e3 = __expf(v3 - mx);
    float sum = e0 + e1 + e2 + e3;
#pragma unroll
    for (int off = 1; off < 16; off <<= 1) sum += __shfl_xor(sum, off, 64);
    float is = 1.0f / sum;
    const int q = w * 16 + lg * 4 + r;
    Ps[q][0 * 16 + li] = f32_to_bf16(e0 * is);
    Ps[q][1 * 16 + li] = f32_to_bf16(e1 * is);
    Ps[q][2 * 16 + li] = f32_to_bf16(e2 * is);
    Ps[q][3 * 16 + li] = f32_to_bf16(e3 * is);
  }
  __syncthreads();

  f32x4 oc[4] = {};
#pragma unroll
  for (int ks = 0; ks < 2; ks++) {
    bf16x8 pa = ld_bf16x8(&Ps[w * 16 + li][ks * 32 + lg * 8]);
#pragma unroll
    for (int n = 0; n < 4; n++) {
      bf16x8 vf = ld_bf16x8(&Vt[n * 16 + li][ks * 32 + lg * 8]);
      oc[n] = __builtin_amdgcn_mfma_f32_16x16x32_bf16(pa, vf, oc[n], 0, 0, 0);
    }
  }
#pragma unroll
  for (int n = 0; n < 4; n++)
#pragma unroll
    for (int r = 0; r < 4; r++)
      ctx[(size_t)(b * 64 + w * 16 + lg * 4 + r) * 1024 + h * 64 + n * 16 + li] =
          f32_to_bf16(oc[n][r]);
}

extern "C" void kernel_launch(void* const* d_in, const int* in_sizes, int n_in,
                              void* d_out, int out_size, void* d_ws, size_t ws_size,
                              hipStream_t stream) {
  const float* x  = (const float*)d_in[0];
  const float* wq = (const float*)d_in[1];
  const float* bq = (const float*)d_in[2];
  const float* wk = (const float*)d_in[3];
  const float* bk = (const float*)d_in[4];
  const float* wv = (const float*)d_in[5];
  const float* bv = (const float*)d_in[6];
  const float* wo = (const float*)d_in[7];
  const float* bo = (const float*)d_in[8];
  float* out = (float*)d_out;

  const int D = 1024;
  const int M = in_sizes[0] / D;  // B*S = 32768

  char* ws = (char*)d_ws;
  unsigned short* xb    = (unsigned short*)ws;
  unsigned short* wqkvT = (unsigned short*)(ws + (size_t)M * 1024 * 2);
  unsigned short* woT   = wqkvT + (size_t)3 * 1024 * 1024;
  unsigned short* Qb    = woT + (size_t)1024 * 1024;
  unsigned short* Kb    = Qb + (size_t)M * 1024;
  unsigned short* Vb    = Kb + (size_t)M * 1024;
  unsigned short* ctx   = xb;  // reuse: x no longer needed after QKV GEMM

  cvt_x<<<2048, 256, 0, stream>>>(x, xb, M * D / 4);
  cvt_w<<<dim3(16, 16, 4), 256, 0, stream>>>(wq, wk, wv, wo, wqkvT, woT);
  gemm8p<0><<<(M / 256) * (3072 / 256), 512, 0, stream>>>(
      xb, wqkvT, bq, bk, bv, Qb, Kb, Vb, nullptr, 3072, 1024);
  attn<<<(M / 64) * 16, 256, 0, stream>>>(Qb, Kb, Vb, ctx);
  gemm8p<1><<<(M / 256) * (1024 / 256), 512, 0, stream>>>(
      ctx, woT, bo, nullptr, nullptr, nullptr, nullptr, nullptr, out, 1024, 1024);
}